// Round 2
// baseline (204.655 us; speedup 1.0000x reference)
//
#include <hip/hip_runtime.h>
#include <math.h>

// R17: R16's coalescing fixes were correct but total didn't move: all three
// big kernels are LATENCY-bound at starvation parallelism (attn occ 40%,
// outcomp/qkv ~1 block/CU). Fixes: (a) attn K-split x2 (2304 blocks): no-max
// O_aug is linear, halves combine via fp32 atomicAdd into zeroed AO + L
// (2 addends/address -> commutative -> deterministic); (b) qkv one matrix
// per block grid(72,4,3)=864 blocks; (c) outcomp 16-token tiles grid(144,2),
// divide-by-l folded into AO staging; (d) wprep+xprep merged into one
// prep_kernel. Tiered ws: split path needs +288KB (L arrays).
#define BATCH 2
#define C 64
#define HH 48
#define WW 48
#define NTOK 2304
#define HEADS 8
#define KVSTRIDE 12

typedef unsigned short bf16_t;
typedef __attribute__((ext_vector_type(8))) short bf16x8;
typedef __attribute__((ext_vector_type(4))) float f32x4;

__device__ __forceinline__ bf16_t f2bf(float f) {
    unsigned int u = __float_as_uint(f);
    u = (u + 0x7fffu + ((u >> 16) & 1u)) >> 16;   // RNE
    return (bf16_t)u;
}
__device__ __forceinline__ unsigned pack2(float a, float b) {
    return (unsigned)f2bf(a) | ((unsigned)f2bf(b) << 16);
}
__device__ __forceinline__ float4 ld_bf4(const bf16_t* p) {
    uint2 v = *(const uint2*)p;
    float4 r;
    r.x = __uint_as_float(v.x << 16); r.y = __uint_as_float(v.x & 0xffff0000u);
    r.z = __uint_as_float(v.y << 16); r.w = __uint_as_float(v.y & 0xffff0000u);
    return r;
}

// Stage one token-row of X (fallback path only).
__device__ __forceinline__ void stage_x_row(
    float* xrow, const float* rgb, const float* dep,
    const float* w_exp, const float* b_exp,
    int b, int n, int strm, int c0, int cstep)
{
    int wi = n / HH, hi = n % HH;
    if (strm == 0) {
        const float* base = rgb + (size_t)b * C * NTOK + (size_t)hi * WW + wi;
        for (int c = c0; c < 64; c += cstep)
            xrow[c] = base[(size_t)c * NTOK];
    } else {
        float cy = 0.5f * hi - 0.25f, cx = 0.5f * wi - 0.25f;
        float fy0 = floorf(cy), fx0 = floorf(cx);
        float fy = cy - fy0, fx = cx - fx0;
        int y0 = max((int)fy0, 0), x0 = max((int)fx0, 0);
        int y1 = min((int)fy0 + 1, 23), x1 = min((int)fx0 + 1, 23);
        const float* dp = dep + b * 576;
        float d00 = dp[y0*24 + x0], d01 = dp[y0*24 + x1];
        float d10 = dp[y1*24 + x0], d11 = dp[y1*24 + x1];
        for (int c = c0; c < 64; c += cstep) {
            float w = w_exp[c], bb = b_exp[c];
            float r00 = fmaxf(w*d00 + bb, 0.f), r01 = fmaxf(w*d01 + bb, 0.f);
            float r10 = fmaxf(w*d10 + bb, 0.f), r11 = fmaxf(w*d11 + bb, 0.f);
            xrow[c] = (1.f-fy)*((1.f-fx)*r00 + fx*r01) + fy*((1.f-fx)*r10 + fx*r11);
        }
    }
}

// ===========================================================================
// MAIN PATH
// ===========================================================================

// Merged xprep (blocks 0..143) + wprep (blocks 144..151). One launch.
// xprep strm0: LDS-tiled transpose rgb [c][hi*48+wi] -> Xt[n=wi*48+hi][c]
// (U stride 65: transpose-read lands 2-way max). strm1: depth bilinear.
// wprep: W1 = Wc[:,:64]@Wrp ; W2 = Wc[:,64:]@Wdp ; beff = Wc@[br;bd]+bc.
__global__ __launch_bounds__(256) void prep_kernel(
    const float* __restrict__ rgb, const float* __restrict__ dep,
    const float* __restrict__ w_exp, const float* __restrict__ b_exp,
    const float* __restrict__ w_rp, const float* __restrict__ w_dp,
    const float* __restrict__ w_comp,
    const float* __restrict__ b_rp, const float* __restrict__ b_dp,
    const float* __restrict__ b_comp,
    float* __restrict__ Xt,
    float* __restrict__ W1, float* __restrict__ W2, float* __restrict__ beff)
{
    __shared__ float U[64*68];
    int bid = blockIdx.x;
    int tid = threadIdx.x;

    if (bid < 144) {
        int t = bid >> 2, z = bid & 3;
        int b = z >> 1, strm = z & 1;
        if (strm == 0) {
            const float* src = rgb + (size_t)b * C * NTOK + t * 64;
            #pragma unroll
            for (int p = 0; p < 4; ++p) {
                int idx = tid + p * 256;
                int c = idx >> 4, m4 = (idx & 15) * 4;
                *(float4*)&U[c*65 + m4] = *(const float4*)&src[(size_t)c * NTOK + m4];
            }
            __syncthreads();
            #pragma unroll
            for (int p = 0; p < 4; ++p) {
                int idx = tid + p * 256;
                int row = idx >> 4, l = idx & 15;
                int mi = t * 64 + row;
                int hi = mi / 48, wi = mi % 48;    // rgb memory coords
                int n  = wi * 48 + hi;             // token index
                float4 v;
                v.x = U[(4*l + 0)*65 + row];
                v.y = U[(4*l + 1)*65 + row];
                v.z = U[(4*l + 2)*65 + row];
                v.w = U[(4*l + 3)*65 + row];
                *(float4*)&Xt[((size_t)z * NTOK + n) * 64 + 4*l] = v;
            }
        } else {
            int tok_l = tid >> 2, cq = (tid & 3) * 16;
            int n = t * 64 + tok_l;
            int wi = n / HH, hi = n % HH;
            float cy = 0.5f * hi - 0.25f, cx = 0.5f * wi - 0.25f;
            float fy0 = floorf(cy), fx0 = floorf(cx);
            float fy = cy - fy0, fx = cx - fx0;
            int y0 = max((int)fy0, 0), x0 = max((int)fx0, 0);
            int y1 = min((int)fy0 + 1, 23), x1 = min((int)fx0 + 1, 23);
            const float* dp = dep + b * 576;
            float d00 = dp[y0*24 + x0], d01 = dp[y0*24 + x1];
            float d10 = dp[y1*24 + x0], d11 = dp[y1*24 + x1];
            float* orow = &Xt[((size_t)z * NTOK + n) * 64];
            #pragma unroll
            for (int cc = 0; cc < 16; cc += 4) {
                float4 v;
                #pragma unroll
                for (int j = 0; j < 4; ++j) {
                    int c = cq + cc + j;
                    float w = w_exp[c], bb = b_exp[c];
                    float r00 = fmaxf(w*d00 + bb, 0.f), r01 = fmaxf(w*d01 + bb, 0.f);
                    float r10 = fmaxf(w*d10 + bb, 0.f), r11 = fmaxf(w*d11 + bb, 0.f);
                    float val = (1.f-fy)*((1.f-fx)*r00 + fx*r01) + fy*((1.f-fx)*r10 + fx*r11);
                    ((float*)&v)[j] = val;
                }
                *(float4*)&orow[cq + cc] = v;
            }
        }
    } else {
        int idx0 = bid - 144;
        int bx = idx0 & 3, m = idx0 >> 2;
        const float* Wp = m ? w_dp : w_rp;
        float* Wo = m ? W2 : W1;
        int sr = tid >> 4, sc4 = (tid & 15) * 4;
        #pragma unroll
        for (int rr = 0; rr < 4; ++rr) {
            int r = rr*16 + sr;
            *(float4*)&U[r*68 + sc4] = *(const float4*)&Wp[r*64 + sc4];
        }
        __syncthreads();
        int r = tid >> 4;
        int o = bx*16 + r;
        int c4 = (tid & 15) * 4;
        float a0 = 0, a1 = 0, a2 = 0, a3 = 0;
        for (int j = 0; j < 64; ++j) {
            float wc = w_comp[o*128 + m*64 + j];
            float4 wp = *(const float4*)&U[j*68 + c4];
            a0 += wc*wp.x; a1 += wc*wp.y; a2 += wc*wp.z; a3 += wc*wp.w;
        }
        Wo[o*64 + c4]     = a0;
        Wo[o*64 + c4 + 1] = a1;
        Wo[o*64 + c4 + 2] = a2;
        Wo[o*64 + c4 + 3] = a3;
        if (bx == 0 && m == 0 && tid < 64) {
            float s = b_comp[tid];
            for (int j = 0; j < 64; ++j)
                s += w_comp[tid*128 + j] * b_rp[j] + w_comp[tid*128 + 64 + j] * b_dp[j];
            beff[tid] = s;
        }
    }
}

// One matrix per block: grid(72, 4, 3) = 864 blocks (was 288 with 3-GEMM
// serial chain). Q,K -> [sb][h][n][8] bf16 (Q pre-scaled); V -> [sb][h][d][n].
__global__ __launch_bounds__(256, 2) void qkv_kernel(
    const float* __restrict__ Xt,
    const float* __restrict__ w_rq, const float* __restrict__ w_rk, const float* __restrict__ w_rv,
    const float* __restrict__ w_dq, const float* __restrict__ w_dk, const float* __restrict__ w_dv,
    bf16_t* __restrict__ Qb, bf16_t* __restrict__ Kb, bf16_t* __restrict__ VT)
{
    int tile = blockIdx.x;           // 0..71 (32 tokens each)
    int z    = blockIdx.y;           // b*2 + strm
    int m    = blockIdx.z;           // 0=Q 1=K 2=V
    int b = z >> 1, strm = z & 1;
    int sb = strm*2 + b;
    const float* W = strm ? (m == 0 ? w_dq : m == 1 ? w_dk : w_dv)
                          : (m == 0 ? w_rq : m == 1 ? w_rk : w_rv);

    __shared__ float Xs[32][68];
    __shared__ float Ws[64][68];
    int tid = threadIdx.x;
    #pragma unroll
    for (int p = 0; p < 2; ++p) {
        int idx = tid + p*256;
        int r = idx >> 4, c4 = (idx & 15) * 4;
        *(float4*)&Xs[r][c4] = *(const float4*)&Xt[((size_t)z*NTOK + tile*32 + r)*64 + c4];
    }
    {
        int sr = tid >> 4, sc = (tid & 15) * 4;
        #pragma unroll
        for (int rr = 0; rr < 4; ++rr) {
            int r = rr*16 + sr;
            *(float4*)&Ws[r][sc] = *(const float4*)&W[r*64 + sc];
        }
    }
    __syncthreads();

    int ty = tid >> 4, tx = tid & 15;
    float acc[2][4] = {};
    #pragma unroll
    for (int k = 0; k < 64; k += 4) {
        float4 xv[2], wv4[4];
        #pragma unroll
        for (int i = 0; i < 2; ++i) xv[i] = *(const float4*)&Xs[2*ty + i][k];
        #pragma unroll
        for (int j = 0; j < 4; ++j) wv4[j] = *(const float4*)&Ws[tx + 16*j][k];
        #pragma unroll
        for (int i = 0; i < 2; ++i)
            #pragma unroll
            for (int j = 0; j < 4; ++j)
                acc[i][j] += xv[i].x*wv4[j].x + xv[i].y*wv4[j].y + xv[i].z*wv4[j].z + xv[i].w*wv4[j].w;
    }
    float scale = (m == 0) ? (0.35355339059327373f * 1.4426950408889634f) : 1.0f;
    #pragma unroll
    for (int j = 0; j < 4; ++j) {
        int o = tx + 16*j;
        int h = o >> 3, d = o & 7;
        #pragma unroll
        for (int i = 0; i < 2; ++i) {
            int n = tile*32 + 2*ty + i;
            bf16_t v = f2bf(acc[i][j] * scale);
            if (m == 0)      Qb[(((size_t)sb*8 + h)*NTOK + n)*8 + d] = v;
            else if (m == 1) Kb[(((size_t)sb*8 + h)*NTOK + n)*8 + d] = v;
            else             VT[(((size_t)sb*8 + h)*8 + d)*NTOK + n] = v;
        }
    }
}

// K-split MFMA flash attention. grid(72, 8, 4): (qt-group x key-half) x head
// x (b*2+which). 4 independent waves; wave w: 16 q x 1152 keys (36 chunks).
// No-max O_aug is LINEAR -> halves combine by fp32 atomicAdd into zeroed
// AO (numerators) + L (denominators). 2 addends/address: deterministic.
__global__ __launch_bounds__(256) void attn_split_kernel(
    const bf16_t* __restrict__ Qb, const bf16_t* __restrict__ Kb,
    const bf16_t* __restrict__ VT,
    float* __restrict__ AOr, float* __restrict__ AOd,
    float* __restrict__ Lr, float* __restrict__ Ld)
{
    int h = blockIdx.y;
    int z = blockIdx.z;
    int b = z >> 1, which = z & 1;
    int qsb = which * 2 + b;
    int ksb = (1 - which) * 2 + b;
    const bf16_t* Q  = Qb + ((size_t)qsb * 8 + h) * NTOK * 8;
    const bf16_t* K  = Kb + ((size_t)ksb * 8 + h) * NTOK * 8;
    const bf16_t* Vt = VT + ((size_t)ksb * 8 + h) * 8 * NTOK;  // [d][key]
    float* AO = which ? AOd : AOr;
    float* Lx = which ? Ld : Lr;

    __shared__ __align__(16) bf16_t Pls[4][16][40];  // padded rows (5 KB)
    __shared__ __align__(16) float  Ols[4][16][16];  // per-wave O tiles (4 KB)

    int tid = threadIdx.x;
    int t = tid & 63, w = tid >> 6;
    int m16 = t & 15, quad = t >> 4;
    int qt = (blockIdx.x >> 1) * 4 + w;    // 0..143
    int kh = blockIdx.x & 1;               // key half
    int n0 = qt * 16;

    const bf16x8 zf = {0,0,0,0,0,0,0,0};
    const bf16x8 onesf = {0x3F80,0x3F80,0x3F80,0x3F80,0x3F80,0x3F80,0x3F80,0x3F80};
    const f32x4 cz = {0.f, 0.f, 0.f, 0.f};

    bf16x8 qf = (quad == 0) ? *(const bf16x8*)&Q[(size_t)(n0 + m16) * 8] : zf;

    f32x4 oacc = cz;

    #pragma unroll 1
    for (int ck = kh*36; ck < kh*36 + 36; ++ck) {
        int k0 = ck * 32;
        bf16x8 kf0 = (quad == 0) ? *(const bf16x8*)&K[(size_t)(k0 + m16) * 8]      : zf;
        bf16x8 kf1 = (quad == 0) ? *(const bf16x8*)&K[(size_t)(k0 + 16 + m16) * 8] : zf;
        bf16x8 vf = (m16 < 8) ? *(const bf16x8*)&Vt[(size_t)m16 * NTOK + k0 + quad * 8]
                  : (m16 == 8 ? onesf : zf);

        f32x4 s0 = __builtin_amdgcn_mfma_f32_16x16x32_bf16(qf, kf0, cz, 0, 0, 0);
        f32x4 s1 = __builtin_amdgcn_mfma_f32_16x16x32_bf16(qf, kf1, cz, 0, 0, 0);

        #pragma unroll
        for (int r = 0; r < 4; ++r) {
            float p0 = __builtin_amdgcn_exp2f(s0[r]);
            float p1 = __builtin_amdgcn_exp2f(s1[r]);
            Pls[w][quad*4 + r][m16]      = (bf16_t)(__float_as_uint(p0) >> 16);
            Pls[w][quad*4 + r][m16 + 16] = (bf16_t)(__float_as_uint(p1) >> 16);
        }
        bf16x8 pf = *(const bf16x8*)&Pls[w][m16][quad * 8];
        oacc = __builtin_amdgcn_mfma_f32_16x16x32_bf16(pf, vf, oacc, 0, 0, 0);
    }

    #pragma unroll
    for (int r = 0; r < 4; ++r)
        Ols[w][quad*4 + r][m16] = oacc[r];
    #pragma unroll
    for (int e = 0; e < 2; ++e) {
        int idx = t * 2 + e;           // 0..127 = 16 q x 8 d
        int qq = idx >> 3, d = idx & 7;
        atomicAdd(&AO[((size_t)b * NTOK + n0 + qq) * 64 + 8 * h + d], Ols[w][qq][d]);
    }
    if (t < 16)
        atomicAdd(&Lx[((size_t)b * NTOK + n0 + t) * 8 + h], Ols[w][t][8]);
}

// T1 attn (no split; normalizes in-kernel). grid(36, 8, 4).
__global__ __launch_bounds__(256) void attn_kernel_t1(
    const bf16_t* __restrict__ Qb, const bf16_t* __restrict__ Kb,
    const bf16_t* __restrict__ VT,
    float* __restrict__ AOr, float* __restrict__ AOd)
{
    int h = blockIdx.y;
    int z = blockIdx.z;
    int b = z >> 1, which = z & 1;
    int qsb = which * 2 + b;
    int ksb = (1 - which) * 2 + b;
    const bf16_t* Q  = Qb + ((size_t)qsb * 8 + h) * NTOK * 8;
    const bf16_t* K  = Kb + ((size_t)ksb * 8 + h) * NTOK * 8;
    const bf16_t* Vt = VT + ((size_t)ksb * 8 + h) * 8 * NTOK;
    float* AO = which ? AOd : AOr;

    __shared__ __align__(16) bf16_t Pls[4][16][40];
    __shared__ __align__(16) float  Ols[4][16][16];

    int tid = threadIdx.x;
    int t = tid & 63, w = tid >> 6;
    int m16 = t & 15, quad = t >> 4;
    int qt = blockIdx.x * 4 + w;
    int n0 = qt * 16;

    const bf16x8 zf = {0,0,0,0,0,0,0,0};
    const bf16x8 onesf = {0x3F80,0x3F80,0x3F80,0x3F80,0x3F80,0x3F80,0x3F80,0x3F80};
    const f32x4 cz = {0.f, 0.f, 0.f, 0.f};

    bf16x8 qf = (quad == 0) ? *(const bf16x8*)&Q[(size_t)(n0 + m16) * 8] : zf;
    f32x4 oacc = cz;

    #pragma unroll 1
    for (int ck = 0; ck < 72; ++ck) {
        int k0 = ck * 32;
        bf16x8 kf0 = (quad == 0) ? *(const bf16x8*)&K[(size_t)(k0 + m16) * 8]      : zf;
        bf16x8 kf1 = (quad == 0) ? *(const bf16x8*)&K[(size_t)(k0 + 16 + m16) * 8] : zf;
        bf16x8 vf = (m16 < 8) ? *(const bf16x8*)&Vt[(size_t)m16 * NTOK + k0 + quad * 8]
                  : (m16 == 8 ? onesf : zf);

        f32x4 s0 = __builtin_amdgcn_mfma_f32_16x16x32_bf16(qf, kf0, cz, 0, 0, 0);
        f32x4 s1 = __builtin_amdgcn_mfma_f32_16x16x32_bf16(qf, kf1, cz, 0, 0, 0);

        #pragma unroll
        for (int r = 0; r < 4; ++r) {
            float p0 = __builtin_amdgcn_exp2f(s0[r]);
            float p1 = __builtin_amdgcn_exp2f(s1[r]);
            Pls[w][quad*4 + r][m16]      = (bf16_t)(__float_as_uint(p0) >> 16);
            Pls[w][quad*4 + r][m16 + 16] = (bf16_t)(__float_as_uint(p1) >> 16);
        }
        bf16x8 pf = *(const bf16x8*)&Pls[w][m16][quad * 8];
        oacc = __builtin_amdgcn_mfma_f32_16x16x32_bf16(pf, vf, oacc, 0, 0, 0);
    }

    #pragma unroll
    for (int r = 0; r < 4; ++r)
        Ols[w][quad*4 + r][m16] = oacc[r];
    #pragma unroll
    for (int e = 0; e < 2; ++e) {
        int idx = t * 2 + e;
        int qq = idx >> 3, d = idx & 7;
        float val = Ols[w][qq][d] / Ols[w][qq][8];
        AO[((size_t)b * NTOK + n0 + qq) * 64 + 8 * h + d] = val;
    }
}

// Fused 2x K=64 GEMM + beff + GELU + LDS-restage + coalesced store.
// grid(144, 2): 16-token tiles (288 blocks, was 144). If Lr!=null, AO holds
// numerators: divide by per-(n,h) denominator during staging.
__global__ __launch_bounds__(256, 2) void outcomp_kernel(
    const float* __restrict__ AOr, const float* __restrict__ AOd,
    const float* __restrict__ Lr, const float* __restrict__ Ld,
    const float* __restrict__ W1, const float* __restrict__ W2,
    const float* __restrict__ beff, float* __restrict__ out)
{
    int tile = blockIdx.x;       // 0..143
    int b    = blockIdx.y;
    int n0 = tile * 16;
    __shared__ float Ar[16][68];
    __shared__ float Ad[16][68];
    __shared__ float W1s[64][68];
    __shared__ float W2s[64][68];
    int tid = threadIdx.x;
    {
        int row = tid >> 4, c4 = (tid & 15) * 4;
        size_t base = (size_t)b*NTOK + n0 + row;
        float4 vr = *(const float4*)&AOr[base*64 + c4];
        float4 vd = *(const float4*)&AOd[base*64 + c4];
        if (Lr) {
            float ir = 1.0f / Lr[base*8 + (c4 >> 3)];
            float id = 1.0f / Ld[base*8 + (c4 >> 3)];
            vr.x *= ir; vr.y *= ir; vr.z *= ir; vr.w *= ir;
            vd.x *= id; vd.y *= id; vd.z *= id; vd.w *= id;
        }
        *(float4*)&Ar[row][c4] = vr;
        *(float4*)&Ad[row][c4] = vd;
    }
    {
        int sr = tid >> 4, sc4 = (tid & 15) * 4;
        #pragma unroll
        for (int rr = 0; rr < 4; ++rr) {
            int r = rr*16 + sr;
            *(float4*)&W1s[r][sc4] = *(const float4*)&W1[r*64 + sc4];
            *(float4*)&W2s[r][sc4] = *(const float4*)&W2[r*64 + sc4];
        }
    }
    __syncthreads();

    int tx = tid & 15, ty = tid >> 4;
    float g[4] = {};
    #pragma unroll
    for (int k = 0; k < 64; k += 4) {
        float4 xr = *(const float4*)&Ar[ty][k];
        float4 xd = *(const float4*)&Ad[ty][k];
        #pragma unroll
        for (int jj = 0; jj < 4; ++jj) {
            float4 w1 = *(const float4*)&W1s[tx + 16*jj][k];
            float4 w2 = *(const float4*)&W2s[tx + 16*jj][k];
            g[jj] += xr.x*w1.x + xr.y*w1.y + xr.z*w1.z + xr.w*w1.w
                   + xd.x*w2.x + xd.y*w2.y + xd.z*w2.z + xd.w*w2.w;
        }
    }

    __syncthreads();                   // done reading W1s/W2s
    float* Gs = &W1s[0][0];            // viewed as [64 o][stride 20]
    #pragma unroll
    for (int jj = 0; jj < 4; ++jj) {
        int o = tx + 16*jj;
        float x = g[jj] + beff[o];
        float gl = 0.5f * x * (1.0f + erff(x * 0.70710678118654752f));
        Gs[o*20 + ty] = gl;
    }
    __syncthreads();
    {
        int o = tid >> 2, s = tid & 3;  // 64 o x 4 float4-segments
        float4 v = *(const float4*)&Gs[o*20 + 4*s];
        *(float4*)&out[((size_t)(b*C + o))*NTOK + n0 + 4*s] = v;
    }
}

// ===========================================================================
// FALLBACK (R9 big path, proven): ws >= 3,538,944 B.
// ===========================================================================
__global__ __launch_bounds__(256) void kv_all_kernel(
    const float* __restrict__ rgb, const float* __restrict__ dep,
    const float* __restrict__ w_exp, const float* __restrict__ b_exp,
    const float* __restrict__ w_rk, const float* __restrict__ w_rv,
    const float* __restrict__ w_dk, const float* __restrict__ w_dv,
    bf16_t* __restrict__ Kr, bf16_t* __restrict__ Vr,
    bf16_t* __restrict__ Kd, bf16_t* __restrict__ Vd)
{
    int tile = blockIdx.x;
    int m    = blockIdx.y;
    int z    = blockIdx.z;
    int b = z >> 1, strm = z & 1;
    const float* W = strm ? (m ? w_dv : w_dk) : (m ? w_rv : w_rk);
    bf16_t* O = (strm ? (m ? Vd : Kd) : (m ? Vr : Kr))
              + ((size_t)b * NTOK + tile * 64) * 64;

    __shared__ float Xs[64][68];
    __shared__ float Ws[64][68];
    int tid = threadIdx.x;
    {
        int r = tid & 63, c0 = tid >> 6;
        stage_x_row(&Xs[r][0], rgb, dep, w_exp, b_exp, b, tile*64 + r, strm, c0, 4);
    }
    int sr = tid >> 4, sc = (tid & 15) * 4;
    #pragma unroll
    for (int rr = 0; rr < 4; ++rr) {
        int r = rr*16 + sr;
        *(float4*)&Ws[r][sc] = *(const float4*)&W[r*64 + sc];
    }
    __syncthreads();

    int ty = tid >> 4, tx = tid & 15;
    float acc[4][4] = {};
    #pragma unroll
    for (int k = 0; k < 64; k += 4) {
        float4 xv[4], wv4[4];
        #pragma unroll
        for (int i = 0; i < 4; ++i) xv[i] = *(const float4*)&Xs[4*ty + i][k];
        #pragma unroll
        for (int j = 0; j < 4; ++j) wv4[j] = *(const float4*)&Ws[tx + 16*j][k];
        #pragma unroll
        for (int i = 0; i < 4; ++i)
            #pragma unroll
            for (int j = 0; j < 4; ++j)
                acc[i][j] += xv[i].x*wv4[j].x + xv[i].y*wv4[j].y + xv[i].z*wv4[j].z + xv[i].w*wv4[j].w;
    }
    #pragma unroll
    for (int i = 0; i < 4; ++i)
        #pragma unroll
        for (int j = 0; j < 4; ++j)
            O[(4*ty + i)*64 + tx + 16*j] = f2bf(acc[i][j]);
}

__global__ __launch_bounds__(256) void attn_all_kernel(
    const float* __restrict__ rgb, const float* __restrict__ dep,
    const float* __restrict__ w_exp, const float* __restrict__ b_exp,
    const float* __restrict__ w_rq, const float* __restrict__ w_dq,
    const bf16_t* __restrict__ Kr, const bf16_t* __restrict__ Vr,
    const bf16_t* __restrict__ Kd, const bf16_t* __restrict__ Vd,
    bf16_t* __restrict__ AOr, bf16_t* __restrict__ AOd)
{
    int qt = blockIdx.x;
    int h  = blockIdx.y;
    int z  = blockIdx.z;
    int b = z >> 1, which = z & 1;
    const float* wq = which ? w_dq : w_rq;
    const bf16_t* K = which ? Kr : Kd;
    const bf16_t* V = which ? Vr : Vd;
    bf16_t* AO      = which ? AOd : AOr;

    __shared__ float Xs[64][68];
    __shared__ float Wqs[8][64];
    __shared__ __align__(16) float Ks[4][64][KVSTRIDE];
    __shared__ __align__(16) float Vs[4][64][KVSTRIDE];

    int tid = threadIdx.x;
    int t = tid & 63;
    int w = tid >> 6;
    int n = qt * 64 + t;

    stage_x_row(&Xs[t][0], rgb, dep, w_exp, b_exp, b, n, which == 0 ? 0 : 1, w, 4);
    if (w == 0) {
        #pragma unroll
        for (int d = 0; d < 8; ++d) Wqs[d][t] = wq[(8*h + d)*64 + t];
    }
    __syncthreads();

    const float sc = 0.35355339059327373f * 1.4426950408889634f;
    float q[8];
    #pragma unroll
    for (int d = 0; d < 8; ++d) {
        float s = 0.f;
        #pragma unroll 8
        for (int c = 0; c < 64; ++c) s += Xs[t][c] * Wqs[d][c];
        q[d] = s * sc;
    }

    float mrun = -INFINITY, l = 0.f;
    float acc[8] = {};

    #pragma unroll 1
    for (int st = 0; st < 9; ++st) {
        __syncthreads();
        {
            size_t g = ((size_t)b * NTOK + (w*576 + st*64 + t)) * 64 + 8 * h;
            *(float4*)&Ks[w][t][0] = ld_bf4(&K[g]);
            *(float4*)&Ks[w][t][4] = ld_bf4(&K[g + 4]);
            *(float4*)&Vs[w][t][0] = ld_bf4(&V[g]);
            *(float4*)&Vs[w][t][4] = ld_bf4(&V[g + 4]);
        }
        __syncthreads();

        for (int g8 = 0; g8 < 8; ++g8) {
            float s[8];
            #pragma unroll
            for (int u = 0; u < 8; ++u) {
                const float4 ka = *(const float4*)&Ks[w][g8*8 + u][0];
                const float4 kb = *(const float4*)&Ks[w][g8*8 + u][4];
                s[u] = q[0]*ka.x + q[1]*ka.y + q[2]*ka.z + q[3]*ka.w
                     + q[4]*kb.x + q[5]*kb.y + q[6]*kb.z + q[7]*kb.w;
            }
            float tm = fmaxf(fmaxf(fmaxf(s[0],s[1]), fmaxf(s[2],s[3])),
                             fmaxf(fmaxf(s[4],s[5]), fmaxf(s[6],s[7])));
            float mn = fmaxf(mrun, tm);
            float alpha = __builtin_amdgcn_exp2f(mrun - mn);
            float ps = 0.f;
            #pragma unroll
            for (int u = 0; u < 8; ++u) { s[u] = __builtin_amdgcn_exp2f(s[u] - mn); ps += s[u]; }
            l = l * alpha + ps;
            #pragma unroll
            for (int d = 0; d < 8; ++d) acc[d] *= alpha;
            #pragma unroll
            for (int u = 0; u < 8; ++u) {
                const float4 va = *(const float4*)&Vs[w][g8*8 + u][0];
                const float4 vb = *(const float4*)&Vs[w][g8*8 + u][4];
                acc[0] += s[u]*va.x; acc[1] += s[u]*va.y; acc[2] += s[u]*va.z; acc[3] += s[u]*va.w;
                acc[4] += s[u]*vb.x; acc[5] += s[u]*vb.y; acc[6] += s[u]*vb.z; acc[7] += s[u]*vb.w;
            }
            mrun = mn;
        }
    }

    float* part = &Xs[0][0];
    __syncthreads();
    {
        float* p = &part[(w*64 + t) * 10];
        p[0] = mrun; p[1] = l;
        #pragma unroll
        for (int d = 0; d < 8; ++d) p[2 + d] = acc[d];
    }
    __syncthreads();
    if (tid < 64) {
        float M = -INFINITY;
        #pragma unroll
        for (int v = 0; v < 4; ++v) M = fmaxf(M, part[(v*64 + t)*10]);
        float L = 0.f, o[8] = {};
        #pragma unroll
        for (int v = 0; v < 4; ++v) {
            const float* p = &part[(v*64 + t)*10];
            float al = __builtin_amdgcn_exp2f(p[0] - M);
            L += p[1] * al;
            #pragma unroll
            for (int d = 0; d < 8; ++d) o[d] += p[2 + d] * al;
        }
        float inv = 1.0f / L;
        uint4 ov;
        ov.x = pack2(o[0]*inv, o[1]*inv);
        ov.y = pack2(o[2]*inv, o[3]*inv);
        ov.z = pack2(o[4]*inv, o[5]*inv);
        ov.w = pack2(o[6]*inv, o[7]*inv);
        *(uint4*)&AO[((size_t)b * NTOK + n) * 64 + 8 * h] = ov;
    }
}

__global__ __launch_bounds__(256) void projcomp_all_kernel(
    const bf16_t* __restrict__ AOr, const bf16_t* __restrict__ AOd,
    const float* __restrict__ w_rp, const float* __restrict__ b_rp,
    const float* __restrict__ w_dp, const float* __restrict__ b_dp,
    const float* __restrict__ w_comp, const float* __restrict__ b_comp,
    float* __restrict__ out)
{
    int tile = blockIdx.x;
    int b    = blockIdx.y;
    __shared__ float A[64][68];
    __shared__ float Bf[64][68];
    __shared__ float Pf[64][68];
    int tid = threadIdx.x;
    int sr = tid >> 4, sc = (tid & 15) * 4;
    int ty = tid >> 4, tx = tid & 15;
    float G[4][4] = {};

    #pragma unroll
    for (int half = 0; half < 2; ++half) {
        const bf16_t* AOx = half ? AOd : AOr;
        const float* Wp   = half ? w_dp : w_rp;
        const float* bp   = half ? b_dp : b_rp;
        #pragma unroll
        for (int rr = 0; rr < 4; ++rr) {
            int r = rr*16 + sr;
            *(float4*)&A[r][sc]  = ld_bf4(&AOx[((size_t)b*NTOK + tile*64 + r)*64 + sc]);
            *(float4*)&Bf[r][sc] = *(const float4*)&Wp[r*64 + sc];
        }
        __syncthreads();
        float acc[4][4] = {};
        #pragma unroll
        for (int k = 0; k < 64; k += 4) {
            float4 xv[4], wv[4];
            #pragma unroll
            for (int i = 0; i < 4; ++i) xv[i] = *(const float4*)&A[4*ty + i][k];
            #pragma unroll
            for (int j = 0; j < 4; ++j) wv[j] = *(const float4*)&Bf[tx + 16*j][k];
            #pragma unroll
            for (int i = 0; i < 4; ++i)
                #pragma unroll
                for (int j = 0; j < 4; ++j)
                    acc[i][j] += xv[i].x*wv[j].x + xv[i].y*wv[j].y + xv[i].z*wv[j].z + xv[i].w*wv[j].w;
        }
        __syncthreads();
        #pragma unroll
        for (int j = 0; j < 4; ++j) {
            float bj = bp[tx + 16*j];
            #pragma unroll
            for (int i = 0; i < 4; ++i)
                Pf[4*ty + i][tx + 16*j] = acc[i][j] + bj;
        }
        #pragma unroll
        for (int rr = 0; rr < 4; ++rr) {
            int r = rr*16 + sr;
            *(float4*)&Bf[r][sc] = *(const float4*)&w_comp[r*128 + half*64 + sc];
        }
        __syncthreads();
        #pragma unroll
        for (int k = 0; k < 64; k += 4) {
            float4 xv[4], wv[4];
            #pragma unroll
            for (int i = 0; i < 4; ++i) xv[i] = *(const float4*)&Pf[4*ty + i][k];
            #pragma unroll
            for (int j = 0; j < 4; ++j) wv[j] = *(const float4*)&Bf[tx + 16*j][k];
            #pragma unroll
            for (int i = 0; i < 4; ++i)
                #pragma unroll
                for (int j = 0; j < 4; ++j)
                    G[i][j] += xv[i].x*wv[j].x + xv[i].y*wv[j].y + xv[i].z*wv[j].z + xv[i].w*wv[j].w;
        }
        __syncthreads();
    }

    #pragma unroll
    for (int j = 0; j < 4; ++j) {
        int o = tx + 16*j;
        float bj = b_comp[o];
        #pragma unroll
        for (int i = 0; i < 4; ++i) {
            int n = tile*64 + 4*ty + i;
            int wi = n / HH, hi = n % HH;
            float x = G[i][j] + bj;
            float g = 0.5f * x * (1.0f + erff(x * 0.70710678118654752f));
            out[((b*C + o)*WW + wi)*HH + hi] = g;
        }
    }
}

// ---------------------------------------------------------------------------
extern "C" void kernel_launch(void* const* d_in, const int* in_sizes, int n_in,
                              void* d_out, int out_size, void* d_ws, size_t ws_size,
                              hipStream_t stream) {
    const float* rgb_fea = (const float*)d_in[0];
    const float* depth   = (const float*)d_in[1];
    const float* w_exp   = (const float*)d_in[2];
    const float* b_exp   = (const float*)d_in[3];
    const float* w_rq    = (const float*)d_in[4];
    const float* w_rk    = (const float*)d_in[5];
    const float* w_rv    = (const float*)d_in[6];
    const float* w_dq    = (const float*)d_in[7];
    const float* w_dk    = (const float*)d_in[8];
    const float* w_dv    = (const float*)d_in[9];
    const float* w_rp    = (const float*)d_in[10];
    const float* b_rp    = (const float*)d_in[11];
    const float* w_dp    = (const float*)d_in[12];
    const float* b_dp    = (const float*)d_in[13];
    const float* w_comp  = (const float*)d_in[14];
    const float* b_comp  = (const float*)d_in[15];
    float* out = (float*)d_out;

    if (ws_size >= 6226176) {
        // T2: K-split attn. Layout:
        //   0        Qb [4][8][2304][8] bf16      (1,179,648)
        //   1179648  Kb                           (1,179,648)
        //   2359296  VT [4][8][8][2304] bf16      (1,179,648)
        //   3538944  AOr [2][2304][64] f32 (numerators; aliases Xt)
        //   4718592  AOd
        //   5898240  Lr [2][2304][8] f32          (147,456)
        //   6045696  Ld                           (147,456)
        //   6193152  W1 / 6209536 W2 / 6225920 beff
        char* Wb = (char*)d_ws;
        bf16_t* Qb  = (bf16_t*)Wb;
        bf16_t* Kb  = (bf16_t*)(Wb + 1179648);
        bf16_t* VT  = (bf16_t*)(Wb + 2359296);
        float* AOr  = (float*)(Wb + 3538944);
        float* AOd  = (float*)(Wb + 4718592);
        float* Lr   = (float*)(Wb + 5898240);
        float* Ld   = (float*)(Wb + 6045696);
        float* W1   = (float*)(Wb + 6193152);
        float* W2   = (float*)(Wb + 6209536);
        float* beff = (float*)(Wb + 6225920);
        float* Xt   = (float*)(Wb + 3538944);   // dead after qkv

        prep_kernel<<<dim3(152), dim3(256), 0, stream>>>(
            rgb_fea, depth, w_exp, b_exp, w_rp, w_dp, w_comp,
            b_rp, b_dp, b_comp, Xt, W1, W2, beff);
        qkv_kernel<<<dim3(72, 4, 3), dim3(256), 0, stream>>>(
            Xt, w_rq, w_rk, w_rv, w_dq, w_dk, w_dv, Qb, Kb, VT);
        // zero AOr+AOd+Lr+Ld (contiguous 3538944..6193152) for atomic accum
        hipMemsetAsync(Wb + 3538944, 0, 2654208, stream);
        attn_split_kernel<<<dim3(72, 8, 4), dim3(256), 0, stream>>>(
            Qb, Kb, VT, AOr, AOd, Lr, Ld);
        outcomp_kernel<<<dim3(144, 2), dim3(256), 0, stream>>>(
            AOr, AOd, Lr, Ld, W1, W2, beff, out);
    } else if (ws_size >= 5931264) {
        // T1: previous main path layout (no L arrays; attn normalizes).
        char* Wb = (char*)d_ws;
        bf16_t* Qb  = (bf16_t*)Wb;
        bf16_t* Kb  = (bf16_t*)(Wb + 1179648);
        bf16_t* VT  = (bf16_t*)(Wb + 2359296);
        float* AOr  = (float*)(Wb + 3538944);
        float* AOd  = (float*)(Wb + 4718592);
        float* W1   = (float*)(Wb + 5898240);
        float* W2   = (float*)(Wb + 5914624);
        float* beff = (float*)(Wb + 5931008);
        float* Xt   = (float*)(Wb + 3538944);

        prep_kernel<<<dim3(152), dim3(256), 0, stream>>>(
            rgb_fea, depth, w_exp, b_exp, w_rp, w_dp, w_comp,
            b_rp, b_dp, b_comp, Xt, W1, W2, beff);
        qkv_kernel<<<dim3(72, 4, 3), dim3(256), 0, stream>>>(
            Xt, w_rq, w_rk, w_rv, w_dq, w_dk, w_dv, Qb, Kb, VT);
        attn_kernel_t1<<<dim3(36, 8, 4), dim3(256), 0, stream>>>(
            Qb, Kb, VT, AOr, AOd);
        outcomp_kernel<<<dim3(144, 2), dim3(256), 0, stream>>>(
            AOr, AOd, (const float*)nullptr, (const float*)nullptr,
            W1, W2, beff, out);
    } else {
        // R9 big path (proven)
        const size_t BUF = (size_t)BATCH * NTOK * 64;
        bf16_t* Kr  = (bf16_t*)d_ws;
        bf16_t* Vr  = Kr + BUF;
        bf16_t* Kd  = Vr + BUF;
        bf16_t* Vd  = Kd + BUF;
        bf16_t* AOr = Vd + BUF;
        bf16_t* AOd = AOr + BUF;
        kv_all_kernel<<<dim3(36, 2, 4), dim3(256), 0, stream>>>(
            rgb_fea, depth, w_exp, b_exp, w_rk, w_rv, w_dk, w_dv, Kr, Vr, Kd, Vd);
        attn_all_kernel<<<dim3(36, 8, 4), dim3(256), 0, stream>>>(
            rgb_fea, depth, w_exp, b_exp, w_rq, w_dq, Kr, Vr, Kd, Vd, AOr, AOd);
        projcomp_all_kernel<<<dim3(36, 2), dim3(256), 0, stream>>>(
            AOr, AOd, w_rp, b_rp, w_dp, b_dp, w_comp, b_comp, out);
    }
}